// Round 5
// baseline (499.596 us; speedup 1.0000x reference)
//
#include <hip/hip_runtime.h>
#include <math.h>

// ---------------------------------------------------------------------------
// Bidirectional Mamba encoder, fp32, round 5.
// - GEMM kernels re-tiled to 16 output rows -> >=2 blocks/CU (k_embed 520,
//   k_out/k_ffn 528 blocks).
// - Scan: 16 chunks of 68 (LP=1088) -> 16 waves/CU; scan2's 8-lane reduce
//   via DPP (quad_perm xor1/xor2 + row_half_mirror) instead of ds_swizzle;
//   scan1 accumulates sum(delta) and takes P = exp(A*sum) once.
// ---------------------------------------------------------------------------

#define L_SEQ 1031
#define LP    1088          // 16 chunks x 68
#define TC    68
#define NCH   16
#define BATCH 8
#define NVAR  1024
#define SEQQ  512
#define TFEAT 7

#define SZ_H    ((size_t)BATCH * L_SEQ * 128)
#define SZ_XZ   ((size_t)2 * BATCH * L_SEQ * 256)
#define SZ_DT   ((size_t)2 * BATCH * 128 * LP)
#define SZ_BC   ((size_t)2 * BATCH * 16 * LP)
#define OFF_H    ((size_t)0)
#define OFF_H1   (OFF_H + SZ_H)
#define OFF_XZ   (OFF_H1 + SZ_H)
#define OFF_XCT  (OFF_XZ + SZ_XZ)
#define OFF_DLT  (OFF_XCT + SZ_DT)
#define OFF_BMT  (OFF_DLT + SZ_DT)
#define OFF_CMT  (OFF_BMT + SZ_BC)
#define OFF_YT   (OFF_CMT + SZ_BC)
// chunk summaries overlay H1: 2 * 524,288 = 1,048,576 <= SZ_H = 1,055,744
#define SZ_SUM  ((size_t)2 * BATCH * NCH * 128 * 16)   // 524,288 floats

__device__ __forceinline__ float silu_f(float x) {
  return x / (1.f + __expf(-x));
}
__device__ __forceinline__ float softplus_f(float x) {
  return (x > 20.f) ? x : log1pf(__expf(x));
}
// 8-lane (lane&7 groups) sum via DPP: xor1, xor2, then half-row mirror
// (valid after xor1/xor2 make each 4-lane group uniform).
__device__ __forceinline__ float red8(float x) {
  x += __int_as_float(__builtin_amdgcn_update_dpp(
      0, __float_as_int(x), 0xB1, 0xF, 0xF, true));   // quad_perm [1,0,3,2]
  x += __int_as_float(__builtin_amdgcn_update_dpp(
      0, __float_as_int(x), 0x4E, 0xF, 0xF, true));   // quad_perm [2,3,0,1]
  x += __int_as_float(__builtin_amdgcn_update_dpp(
      0, __float_as_int(x), 0x141, 0xF, 0xF, true));  // row_half_mirror
  return x;
}

#define GEMM_INNER(AS, WS, ACC)                                   \
  _Pragma("unroll")                                               \
  for (int k = 0; k < 32; k++) {                                  \
    float2 a = *(const float2*)&AS[k][tt * 2];                    \
    float4 w0 = *(const float4*)&WS[k][tm * 4];                   \
    float4 w1 = *(const float4*)&WS[k][64 + tm * 4];              \
    ACC[0][0] = fmaf(a.x, w0.x, ACC[0][0]);                       \
    ACC[0][1] = fmaf(a.x, w0.y, ACC[0][1]);                       \
    ACC[0][2] = fmaf(a.x, w0.z, ACC[0][2]);                       \
    ACC[0][3] = fmaf(a.x, w0.w, ACC[0][3]);                       \
    ACC[0][4] = fmaf(a.x, w1.x, ACC[0][4]);                       \
    ACC[0][5] = fmaf(a.x, w1.y, ACC[0][5]);                       \
    ACC[0][6] = fmaf(a.x, w1.z, ACC[0][6]);                       \
    ACC[0][7] = fmaf(a.x, w1.w, ACC[0][7]);                       \
    ACC[1][0] = fmaf(a.y, w0.x, ACC[1][0]);                       \
    ACC[1][1] = fmaf(a.y, w0.y, ACC[1][1]);                       \
    ACC[1][2] = fmaf(a.y, w0.z, ACC[1][2]);                       \
    ACC[1][3] = fmaf(a.y, w0.w, ACC[1][3]);                       \
    ACC[1][4] = fmaf(a.y, w1.x, ACC[1][4]);                       \
    ACC[1][5] = fmaf(a.y, w1.y, ACC[1][5]);                       \
    ACC[1][6] = fmaf(a.y, w1.z, ACC[1][6]);                       \
    ACC[1][7] = fmaf(a.y, w1.w, ACC[1][7]);                       \
  }

// single-output-row inner: a broadcast per row tt (16 rows)
#define GEMM_INNER1(AS, WS, ACC)                                  \
  _Pragma("unroll")                                               \
  for (int k = 0; k < 32; k++) {                                  \
    float a = AS[k][tt];                                          \
    float4 w0 = *(const float4*)&WS[k][tm * 4];                   \
    float4 w1 = *(const float4*)&WS[k][64 + tm * 4];              \
    ACC[0] = fmaf(a, w0.x, ACC[0]);                               \
    ACC[1] = fmaf(a, w0.y, ACC[1]);                               \
    ACC[2] = fmaf(a, w0.z, ACC[2]);                               \
    ACC[3] = fmaf(a, w0.w, ACC[3]);                               \
    ACC[4] = fmaf(a, w1.x, ACC[4]);                               \
    ACC[5] = fmaf(a, w1.y, ACC[5]);                               \
    ACC[6] = fmaf(a, w1.z, ACC[6]);                               \
    ACC[7] = fmaf(a, w1.w, ACC[7]);                               \
  }

// ---------------------------------------------------------------------------
// k_embed: H[b,v,:] = token(b,v,:) @ emb_w.T + emb_b. 16-row tiles,
// grid (65, 8), block 256 -> 520 blocks (2/CU).
// ---------------------------------------------------------------------------
__global__ __launch_bounds__(256) void k_embed(
    const float* __restrict__ x_enc, const float* __restrict__ x_mark,
    const float* __restrict__ emb_w, const float* __restrict__ emb_b,
    float* __restrict__ H) {
  int b = blockIdx.y;
  int v0 = blockIdx.x * 16;
  int tid = threadIdx.x;
  int tm = tid & 15, tt = tid >> 4;
  __shared__ float As[32][20];    // [s][v]
  __shared__ float Ws[32][132];   // [s][m]
  float acc[8] = {0.f};
  for (int s0 = 0; s0 < SEQQ; s0 += 32) {
    if (tid < 128) {
      int v4 = tid & 3, s = tid >> 2;
      int vg = v0 + v4 * 4;
      if (vg + 3 < NVAR) {
        float4 x = *(const float4*)&x_enc[((size_t)b * SEQQ + s0 + s) * NVAR + vg];
        if (x.x == -9999.f) x.x = -1.f;
        if (x.y == -9999.f) x.y = -1.f;
        if (x.z == -9999.f) x.z = -1.f;
        if (x.w == -9999.f) x.w = -1.f;
        As[s][v4 * 4 + 0] = x.x;
        As[s][v4 * 4 + 1] = x.y;
        As[s][v4 * 4 + 2] = x.z;
        As[s][v4 * 4 + 3] = x.w;
      } else {
#pragma unroll
        for (int u = 0; u < 4; u++) {
          int v = vg + u;
          float val = 0.f;
          if (v < L_SEQ)
            val = x_mark[((size_t)b * SEQQ + s0 + s) * TFEAT + (v - NVAR)];
          As[s][v4 * 4 + u] = val;
        }
      }
    }
    for (int i = 0; i < 4; i++) {
      int e = tid + i * 256;
      int m = e >> 3, k4 = e & 7;
      float4 w = *(const float4*)&emb_w[(size_t)m * SEQQ + s0 + k4 * 4];
      Ws[k4 * 4 + 0][m] = w.x;
      Ws[k4 * 4 + 1][m] = w.y;
      Ws[k4 * 4 + 2][m] = w.z;
      Ws[k4 * 4 + 3][m] = w.w;
    }
    __syncthreads();
    GEMM_INNER1(As, Ws, acc);
    __syncthreads();
  }
  int v = v0 + tt;
  if (v < L_SEQ) {
    float* dst = &H[((size_t)b * L_SEQ + v) * 128];
    float4 o0 = make_float4(acc[0] + emb_b[tm * 4 + 0],
                            acc[1] + emb_b[tm * 4 + 1],
                            acc[2] + emb_b[tm * 4 + 2],
                            acc[3] + emb_b[tm * 4 + 3]);
    float4 o1 = make_float4(acc[4] + emb_b[64 + tm * 4 + 0],
                            acc[5] + emb_b[64 + tm * 4 + 1],
                            acc[6] + emb_b[64 + tm * 4 + 2],
                            acc[7] + emb_b[64 + tm * 4 + 3]);
    *(float4*)&dst[tm * 4] = o0;
    *(float4*)&dst[64 + tm * 4] = o1;
  }
}

// ---------------------------------------------------------------------------
// k_xz  (round-3, proven; already 1056 blocks = 4/CU)
// ---------------------------------------------------------------------------
__global__ __launch_bounds__(256) void k_xz(
    const float* __restrict__ H, const float* __restrict__ ipw,
    float* __restrict__ XZ, int l) {
  int b = blockIdx.y;
  int dir = blockIdx.z >> 1, nh = blockIdx.z & 1;
  int t0 = blockIdx.x * 32;
  int tid = threadIdx.x;
  int tm = tid & 15, tt = tid >> 4;
  __shared__ float As[32][36];
  __shared__ float Ws[32][132];
  float acc[2][8] = {{0.f}};
  const float* wbase = ipw + (size_t)(l * 2 + dir) * 256 * 128 + (size_t)nh * 128 * 128;
  for (int k0 = 0; k0 < 128; k0 += 32) {
    {
      int row = tid >> 3, k4 = tid & 7;
      int t = t0 + row;
      float4 hv = make_float4(0.f, 0.f, 0.f, 0.f);
      if (t < L_SEQ) {
        int st = dir ? (L_SEQ - 1 - t) : t;
        hv = *(const float4*)&H[((size_t)b * L_SEQ + st) * 128 + k0 + k4 * 4];
      }
      As[k4 * 4 + 0][row] = hv.x;
      As[k4 * 4 + 1][row] = hv.y;
      As[k4 * 4 + 2][row] = hv.z;
      As[k4 * 4 + 3][row] = hv.w;
    }
    for (int i = 0; i < 4; i++) {
      int e = tid + i * 256;
      int n = e >> 3, k4 = e & 7;
      float4 w = *(const float4*)&wbase[(size_t)n * 128 + k0 + k4 * 4];
      Ws[k4 * 4 + 0][n] = w.x;
      Ws[k4 * 4 + 1][n] = w.y;
      Ws[k4 * 4 + 2][n] = w.z;
      Ws[k4 * 4 + 3][n] = w.w;
    }
    __syncthreads();
    GEMM_INNER(As, Ws, acc);
    __syncthreads();
  }
#pragma unroll
  for (int r = 0; r < 2; r++) {
    int t = t0 + tt * 2 + r;
    if (t < L_SEQ) {
      float* dst = XZ + ((size_t)(dir * BATCH + b) * L_SEQ + t) * 256 + nh * 128;
      *(float4*)&dst[tm * 4] = *(float4*)&acc[r][0];
      *(float4*)&dst[64 + tm * 4] = *(float4*)&acc[r][4];
    }
  }
}

// ---------------------------------------------------------------------------
// k_mid  (round-3, proven; grid (34,8,2) to cover LP=1088)
// ---------------------------------------------------------------------------
__global__ __launch_bounds__(256) void k_mid(
    const float* __restrict__ XZ,
    const float* __restrict__ conv_w, const float* __restrict__ conv_b,
    const float* __restrict__ xpw,
    const float* __restrict__ dpw, const float* __restrict__ dpb,
    float* __restrict__ XCT, float* __restrict__ DLT,
    float* __restrict__ BmT, float* __restrict__ CmT, int l) {
  int b = blockIdx.y, dir = blockIdx.z;
  int t0 = blockIdx.x * 32;
  int tid = threadIdx.x;
  int pg = l * 2 + dir;
  __shared__ float xcs[32][132];
  __shared__ float xpws[40][128];
  __shared__ float dbcs[40][36];
  const float* xz = XZ + (size_t)(dir * BATCH + b) * L_SEQ * 256;

  for (int i = 0; i < 20; i++) {
    int e = tid + i * 256;
    int k = e & 127, j = e >> 7;
    xpws[j][k] = xpw[((size_t)pg * 40 + j) * 128 + k];
  }
  for (int i = 0; i < 16; i++) {
    int e = tid + i * 256;
    int d = e & 127, tl = e >> 7;
    int t = t0 + tl;
    float v = 0.f;
    if (t < L_SEQ) {
      float x1 = xz[(size_t)t * 256 + d];
      float x0 = (t > 0) ? xz[(size_t)(t - 1) * 256 + d] : 0.f;
      float c0 = conv_w[((size_t)pg * 128 + d) * 2 + 0];
      float c1 = conv_w[((size_t)pg * 128 + d) * 2 + 1];
      v = silu_f(x0 * c0 + x1 * c1 + conv_b[(size_t)pg * 128 + d]);
    }
    xcs[tl][d] = v;
  }
  __syncthreads();
  {
    int tl = tid & 31, jg = tid >> 5;
    float acc[5] = {0.f};
    const float4* xrow = (const float4*)&xcs[tl][0];
    for (int kk = 0; kk < 32; kk++) {
      float4 a = xrow[kk];
#pragma unroll
      for (int jj = 0; jj < 5; jj++) {
        float4 w = ((const float4*)&xpws[jg * 5 + jj][0])[kk];
        acc[jj] = fmaf(a.x, w.x, acc[jj]);
        acc[jj] = fmaf(a.y, w.y, acc[jj]);
        acc[jj] = fmaf(a.z, w.z, acc[jj]);
        acc[jj] = fmaf(a.w, w.w, acc[jj]);
      }
    }
#pragma unroll
    for (int jj = 0; jj < 5; jj++) dbcs[jg * 5 + jj][tl] = acc[jj];
  }
  __syncthreads();
  for (int i = 0; i < 4; i++) {
    int e = tid + i * 256;
    int tl = e & 31, r = e >> 5;
    int n = r & 15, isC = r >> 4;
    int t = t0 + tl;
    if (t < LP) {
      float v = dbcs[8 + isC * 16 + n][tl];
      float* dst = isC ? CmT : BmT;
      dst[((size_t)(dir * BATCH + b) * 16 + n) * LP + t] = v;
    }
  }
  {
    int d = tid & 127, th = tid >> 7;
    float dw[8];
#pragma unroll
    for (int k = 0; k < 8; k++) dw[k] = dpw[((size_t)pg * 128 + d) * 8 + k];
    float dbv = dpb[(size_t)pg * 128 + d];
    size_t base = ((size_t)(dir * BATCH + b) * 128 + d) * LP;
    for (int tb = th * 16; tb < th * 16 + 16; tb += 4) {
      int t = t0 + tb;
      if (t < LP) {
        float dv[4], xv[4];
#pragma unroll
        for (int u = 0; u < 4; u++) {
          int tl = tb + u;
          float a = dbv;
#pragma unroll
          for (int k = 0; k < 8; k++) a = fmaf(dbcs[k][tl], dw[k], a);
          dv[u] = softplus_f(a);
          xv[u] = xcs[tl][d];
        }
        *(float4*)(DLT + base + t) = make_float4(dv[0], dv[1], dv[2], dv[3]);
        *(float4*)(XCT + base + t) = make_float4(xv[0], xv[1], xv[2], xv[3]);
      }
    }
  }
}

// ---------------------------------------------------------------------------
// k_scan1: pass 1. Local recurrence from h=0 over TC=68; P via log-space
// (sum of delta, shared across n). grid (16, 8, 32) z=(dir,chunk), blk 64.
// ---------------------------------------------------------------------------
__global__ __launch_bounds__(64) void k_scan1(
    const float* __restrict__ DLT, const float* __restrict__ XCT,
    const float* __restrict__ BmT,
    const float* __restrict__ A_log,
    float* __restrict__ sumH, float* __restrict__ sumP, int l) {
  int z = blockIdx.z;
  int dir = z >> 4, j = z & 15;
  int b = blockIdx.y;
  int lane = threadIdx.x;
  int np = lane & 7, ds = lane >> 3;
  int d = blockIdx.x * 8 + ds;
  int pg = l * 2 + dir;
  int n0 = np * 2;
  float A0 = -__expf(A_log[((size_t)pg * 128 + d) * 16 + n0]);
  float A1 = -__expf(A_log[((size_t)pg * 128 + d) * 16 + n0 + 1]);
  size_t bd = ((size_t)(dir * BATCH + b) * 128 + d) * LP + (size_t)j * TC;
  size_t bn = ((size_t)(dir * BATCH + b) * 16 + n0) * LP + (size_t)j * TC;
  const float4* dl4 = (const float4*)(DLT + bd);
  const float4* xc4 = (const float4*)(XCT + bd);
  const float4* b04 = (const float4*)(BmT + bn);
  const float4* b14 = (const float4*)(BmT + bn + LP);
  float h0 = 0.f, h1 = 0.f, sdl = 0.f;
  const int NI = TC / 4;   // 17
  float4 cd = dl4[0], cx = xc4[0], cb0 = b04[0], cb1 = b14[0];
#define P1STEP(DL, XC, B0, B1)                       \
  {                                                  \
    float du_ = (DL) * (XC);                         \
    h0 = fmaf(__expf((DL) * A0), h0, du_ * (B0));    \
    h1 = fmaf(__expf((DL) * A1), h1, du_ * (B1));    \
  }
  for (int i = 0; i < NI; i++) {
    float4 nd = cd, nx = cx, nb0 = cb0, nb1 = cb1;
    if (i + 1 < NI) {
      nd = dl4[i + 1]; nx = xc4[i + 1];
      nb0 = b04[i + 1]; nb1 = b14[i + 1];
    }
    P1STEP(cd.x, cx.x, cb0.x, cb1.x);
    P1STEP(cd.y, cx.y, cb0.y, cb1.y);
    P1STEP(cd.z, cx.z, cb0.z, cb1.z);
    P1STEP(cd.w, cx.w, cb0.w, cb1.w);
    sdl += (cd.x + cd.y) + (cd.z + cd.w);
    cd = nd; cx = nx; cb0 = nb0; cb1 = nb1;
  }
#undef P1STEP
  size_t si = (((size_t)(dir * BATCH + b) * NCH + j) * 128 + d) * 16 + n0;
  *(float2*)&sumH[si] = make_float2(h0, h1);
  *(float2*)&sumP[si] = make_float2(__expf(A0 * sdl), __expf(A1 * sdl));
}

// ---------------------------------------------------------------------------
// k_scan2: pass 2. Rebuild chunk init (<=15 fma), re-run chunk, DPP-reduce
// over n, gate with silu(z), write YT. grid (16, 8, 32), block 64.
// ---------------------------------------------------------------------------
__global__ __launch_bounds__(64) void k_scan2(
    const float* __restrict__ DLT, const float* __restrict__ XCT,
    const float* __restrict__ BmT, const float* __restrict__ CmT,
    const float* __restrict__ XZ,
    const float* __restrict__ A_log, const float* __restrict__ Dpar,
    const float* __restrict__ sumH, const float* __restrict__ sumP,
    float* __restrict__ YT, int l) {
  int z = blockIdx.z;
  int dir = z >> 4, j = z & 15;
  int b = blockIdx.y;
  int lane = threadIdx.x;
  int np = lane & 7, ds = lane >> 3;
  int d = blockIdx.x * 8 + ds;
  int pg = l * 2 + dir;
  int n0 = np * 2;
  float A0 = -__expf(A_log[((size_t)pg * 128 + d) * 16 + n0]);
  float A1 = -__expf(A_log[((size_t)pg * 128 + d) * 16 + n0 + 1]);
  float Dv = Dpar[(size_t)pg * 128 + d];
  float h0 = 0.f, h1 = 0.f;
  {
    size_t sbase = ((size_t)(dir * BATCH + b) * NCH) * 2048 + (size_t)d * 16 + n0;
    for (int jj = 0; jj < j; jj++) {
      float2 hE = *(const float2*)&sumH[sbase + (size_t)jj * 2048];
      float2 Pp = *(const float2*)&sumP[sbase + (size_t)jj * 2048];
      h0 = fmaf(Pp.x, h0, hE.x);
      h1 = fmaf(Pp.y, h1, hE.y);
    }
  }
  size_t bd = ((size_t)(dir * BATCH + b) * 128 + d) * LP + (size_t)j * TC;
  size_t bn = ((size_t)(dir * BATCH + b) * 16 + n0) * LP + (size_t)j * TC;
  const float4* dl4 = (const float4*)(DLT + bd);
  const float4* xc4 = (const float4*)(XCT + bd);
  const float4* b04 = (const float4*)(BmT + bn);
  const float4* b14 = (const float4*)(BmT + bn + LP);
  const float4* c04 = (const float4*)(CmT + bn);
  const float4* c14 = (const float4*)(CmT + bn + LP);
  const float* zbase = XZ + (size_t)(dir * BATCH + b) * L_SEQ * 256 + 128 + d
                       + (size_t)j * TC * 256;
  float4* y4 = (float4*)(YT + bd);
  const int NI = TC / 4;   // 17
  float4 cd = dl4[0], cx = xc4[0], cb0 = b04[0], cb1 = b14[0];
  float4 cc0 = c04[0], cc1 = c14[0];
  float zc[4], zn[4];
  if (np == 0) {
#pragma unroll
    for (int u = 0; u < 4; u++) zc[u] = zbase[(size_t)u * 256];
  }
#define STEP1(DL, XC, B0, B1, C0, C1, YO)            \
  {                                                  \
    float du_ = (DL) * (XC);                         \
    h0 = fmaf(__expf((DL) * A0), h0, du_ * (B0));    \
    h1 = fmaf(__expf((DL) * A1), h1, du_ * (B1));    \
    float p_ = red8(fmaf(h1, (C1), h0 * (C0)));      \
    (YO) = fmaf(Dv, (XC), p_);                       \
  }
  for (int i = 0; i < NI; i++) {
    float4 nd = cd, nx = cx, nb0 = cb0, nb1 = cb1, nc0 = cc0, nc1 = cc1;
    if (i + 1 < NI) {
      nd = dl4[i + 1]; nx = xc4[i + 1];
      nb0 = b04[i + 1]; nb1 = b14[i + 1];
      nc0 = c04[i + 1]; nc1 = c14[i + 1];
      if (np == 0) {
        int tb = (i + 1) * 4;
        // pad-t z reads land in XCT (finite); result only reaches discarded
        // YT pad columns.
#pragma unroll
        for (int u = 0; u < 4; u++) zn[u] = zbase[(size_t)(tb + u) * 256];
      }
    }
    float4 y;
    STEP1(cd.x, cx.x, cb0.x, cb1.x, cc0.x, cc1.x, y.x);
    STEP1(cd.y, cx.y, cb0.y, cb1.y, cc0.y, cc1.y, y.y);
    STEP1(cd.z, cx.z, cb0.z, cb1.z, cc0.z, cc1.z, y.z);
    STEP1(cd.w, cx.w, cb0.w, cb1.w, cc0.w, cc1.w, y.w);
    if (np == 0) {
      y.x *= silu_f(zc[0]);
      y.y *= silu_f(zc[1]);
      y.z *= silu_f(zc[2]);
      y.w *= silu_f(zc[3]);
      y4[i] = y;
#pragma unroll
      for (int u = 0; u < 4; u++) zc[u] = zn[u];
    }
    cd = nd; cx = nx; cb0 = nb0; cb1 = nb1; cc0 = nc0; cc1 = nc1;
  }
#undef STEP1
}

// ---------------------------------------------------------------------------
// k_out: H1 = LN1( H + Yf@opw_f.T + Yr@opw_r.T ). 16-row tiles,
// grid (66, 8), block 256 -> 528 blocks.
// ---------------------------------------------------------------------------
__global__ __launch_bounds__(256) void k_out(
    const float* __restrict__ YT, const float* __restrict__ Hin,
    const float* __restrict__ opw,
    const float* __restrict__ n1w, const float* __restrict__ n1b,
    float* __restrict__ H1, int l) {
  int b = blockIdx.y;
  int t0 = blockIdx.x * 16;
  int tid = threadIdx.x;
  int tm = tid & 15, tt = tid >> 4;
  __shared__ float As[32][20];
  __shared__ float Ws[32][132];
  float acc[8] = {0.f};
  for (int kt = 0; kt < 8; kt++) {
    int dirp = kt >> 2;
    int k0 = (kt & 3) * 32;
    if (tid < 128) {
      int krow = tid >> 2, t4 = tid & 3;
      size_t rowbase = ((size_t)(dirp * BATCH + b) * 128 + k0 + krow) * LP;
      if (dirp == 0) {
        float4 y = *(const float4*)(YT + rowbase + t0 + t4 * 4);
        As[krow][t4 * 4 + 0] = y.x;
        As[krow][t4 * 4 + 1] = y.y;
        As[krow][t4 * 4 + 2] = y.z;
        As[krow][t4 * 4 + 3] = y.w;
      } else {
        int tg = t0 + t4 * 4;
#pragma unroll
        for (int u = 0; u < 4; u++) {
          int src = (L_SEQ - 1) - (tg + u);
          As[krow][t4 * 4 + u] = (src >= 0) ? YT[rowbase + src] : 0.f;
        }
      }
    }
    const float* wsrc = opw + (size_t)(l * 2 + dirp) * 128 * 128;
    for (int i = 0; i < 4; i++) {
      int e = tid + i * 256;
      int n = e >> 3, k4 = e & 7;
      float4 w = *(const float4*)&wsrc[(size_t)n * 128 + k0 + k4 * 4];
      Ws[k4 * 4 + 0][n] = w.x;
      Ws[k4 * 4 + 1][n] = w.y;
      Ws[k4 * 4 + 2][n] = w.z;
      Ws[k4 * 4 + 3][n] = w.w;
    }
    __syncthreads();
    GEMM_INNER1(As, Ws, acc);
    __syncthreads();
  }
  const float* nw = n1w + l * 128;
  const float* nb = n1b + l * 128;
  int t = t0 + tt;
  float4 h0 = make_float4(0.f, 0.f, 0.f, 0.f);
  float4 h1 = make_float4(0.f, 0.f, 0.f, 0.f);
  if (t < L_SEQ) {
    const float* hp = &Hin[((size_t)b * L_SEQ + t) * 128];
    h0 = *(const float4*)&hp[tm * 4];
    h1 = *(const float4*)&hp[64 + tm * 4];
  }
  float v[8];
  v[0] = acc[0] + h0.x; v[1] = acc[1] + h0.y;
  v[2] = acc[2] + h0.z; v[3] = acc[3] + h0.w;
  v[4] = acc[4] + h1.x; v[5] = acc[5] + h1.y;
  v[6] = acc[6] + h1.z; v[7] = acc[7] + h1.w;
  float s1 = 0.f, s2 = 0.f;
#pragma unroll
  for (int jq = 0; jq < 8; jq++) { s1 += v[jq]; s2 += v[jq] * v[jq]; }
#pragma unroll
  for (int msk = 1; msk < 16; msk <<= 1) {
    s1 += __shfl_xor(s1, msk);
    s2 += __shfl_xor(s2, msk);
  }
  float mean = s1 * (1.f / 128.f);
  float rstd = rsqrtf(s2 * (1.f / 128.f) - mean * mean + 1e-5f);
  if (t < L_SEQ) {
    float* dst = &H1[((size_t)b * L_SEQ + t) * 128];
    float4 o0 = make_float4((v[0] - mean) * rstd * nw[tm * 4 + 0] + nb[tm * 4 + 0],
                            (v[1] - mean) * rstd * nw[tm * 4 + 1] + nb[tm * 4 + 1],
                            (v[2] - mean) * rstd * nw[tm * 4 + 2] + nb[tm * 4 + 2],
                            (v[3] - mean) * rstd * nw[tm * 4 + 3] + nb[tm * 4 + 3]);
    float4 o1 = make_float4((v[4] - mean) * rstd * nw[64 + tm * 4 + 0] + nb[64 + tm * 4 + 0],
                            (v[5] - mean) * rstd * nw[64 + tm * 4 + 1] + nb[64 + tm * 4 + 1],
                            (v[6] - mean) * rstd * nw[64 + tm * 4 + 2] + nb[64 + tm * 4 + 2],
                            (v[7] - mean) * rstd * nw[64 + tm * 4 + 3] + nb[64 + tm * 4 + 3]);
    *(float4*)&dst[tm * 4] = o0;
    *(float4*)&dst[64 + tm * 4] = o1;
  }
}

// ---------------------------------------------------------------------------
// k_ffn: H = LN2( h1 + relu(h1@w1.T+b1)@w2.T + b2 ). 16-row tiles,
// grid (66, 8), block 256.
// ---------------------------------------------------------------------------
__global__ __launch_bounds__(256) void k_ffn(
    const float* __restrict__ H1, const float* __restrict__ w1,
    const float* __restrict__ b1, const float* __restrict__ w2,
    const float* __restrict__ b2, const float* __restrict__ n2w,
    const float* __restrict__ n2b, float* __restrict__ Hout, int l) {
  int b = blockIdx.y;
  int t0 = blockIdx.x * 16;
  int tid = threadIdx.x;
  int tm = tid & 15, tt = tid >> 4;
  __shared__ float As[32][20];
  __shared__ float Ws[32][132];
  __shared__ float Ut[128][20];
  float acc[8] = {0.f};
  const float* w1b = w1 + (size_t)l * 128 * 128;
  for (int k0 = 0; k0 < 128; k0 += 32) {
    if (tid < 128) {
      int row = tid >> 3, k4 = tid & 7;
      int t = t0 + row;
      float4 hv = make_float4(0.f, 0.f, 0.f, 0.f);
      if (t < L_SEQ)
        hv = *(const float4*)&H1[((size_t)b * L_SEQ + t) * 128 + k0 + k4 * 4];
      As[k4 * 4 + 0][row] = hv.x;
      As[k4 * 4 + 1][row] = hv.y;
      As[k4 * 4 + 2][row] = hv.z;
      As[k4 * 4 + 3][row] = hv.w;
    }
    for (int i = 0; i < 4; i++) {
      int e = tid + i * 256;
      int n = e >> 3, k4 = e & 7;
      float4 w = *(const float4*)&w1b[(size_t)n * 128 + k0 + k4 * 4];
      Ws[k4 * 4 + 0][n] = w.x;
      Ws[k4 * 4 + 1][n] = w.y;
      Ws[k4 * 4 + 2][n] = w.z;
      Ws[k4 * 4 + 3][n] = w.w;
    }
    __syncthreads();
    GEMM_INNER1(As, Ws, acc);
    __syncthreads();
  }
#pragma unroll
  for (int jq = 0; jq < 4; jq++) {
    int f0 = tm * 4 + jq;
    int f1 = 64 + tm * 4 + jq;
    Ut[f0][tt] = fmaxf(acc[jq] + b1[l * 128 + f0], 0.f);
    Ut[f1][tt] = fmaxf(acc[4 + jq] + b1[l * 128 + f1], 0.f);
    acc[jq] = 0.f;
    acc[4 + jq] = 0.f;
  }
  __syncthreads();
  const float* w2b = w2 + (size_t)l * 128 * 128;
  for (int k0 = 0; k0 < 128; k0 += 32) {
    for (int i = 0; i < 4; i++) {
      int e = tid + i * 256;
      int n = e >> 3, k4 = e & 7;
      float4 w = *(const float4*)&w2b[(size_t)n * 128 + k0 + k4 * 4];
      Ws[k4 * 4 + 0][n] = w.x;
      Ws[k4 * 4 + 1][n] = w.y;
      Ws[k4 * 4 + 2][n] = w.z;
      Ws[k4 * 4 + 3][n] = w.w;
    }
    __syncthreads();
#pragma unroll
    for (int k = 0; k < 32; k++) {
      float a = Ut[k0 + k][tt];
      float4 w0 = *(const float4*)&Ws[k][tm * 4];
      float4 w1v = *(const float4*)&Ws[k][64 + tm * 4];
      acc[0] = fmaf(a, w0.x, acc[0]);
      acc[1] = fmaf(a, w0.y, acc[1]);
      acc[2] = fmaf(a, w0.z, acc[2]);
      acc[3] = fmaf(a, w0.w, acc[3]);
      acc[4] = fmaf(a, w1v.x, acc[4]);
      acc[5] = fmaf(a, w1v.y, acc[5]);
      acc[6] = fmaf(a, w1v.z, acc[6]);
      acc[7] = fmaf(a, w1v.w, acc[7]);
    }
    __syncthreads();
  }
  const float* nw = n2w + l * 128;
  const float* nb = n2b + l * 128;
  int t = t0 + tt;
  float4 h0 = make_float4(0.f, 0.f, 0.f, 0.f);
  float4 h1 = make_float4(0.f, 0.f, 0.f, 0.f);
  if (t < L_SEQ) {
    const float* hp = &H1[((size_t)b * L_SEQ + t) * 128];
    h0 = *(const float4*)&hp[tm * 4];
    h1 = *(const float4*)&hp[64 + tm * 4];
  }
  float v[8];
  v[0] = acc[0] + b2[l * 128 + tm * 4 + 0] + h0.x;
  v[1] = acc[1] + b2[l * 128 + tm * 4 + 1] + h0.y;
  v[2] = acc[2] + b2[l * 128 + tm * 4 + 2] + h0.z;
  v[3] = acc[3] + b2[l * 128 + tm * 4 + 3] + h0.w;
  v[4] = acc[4] + b2[l * 128 + 64 + tm * 4 + 0] + h1.x;
  v[5] = acc[5] + b2[l * 128 + 64 + tm * 4 + 1] + h1.y;
  v[6] = acc[6] + b2[l * 128 + 64 + tm * 4 + 2] + h1.z;
  v[7] = acc[7] + b2[l * 128 + 64 + tm * 4 + 3] + h1.w;
  float s1 = 0.f, s2 = 0.f;
#pragma unroll
  for (int jq = 0; jq < 8; jq++) { s1 += v[jq]; s2 += v[jq] * v[jq]; }
#pragma unroll
  for (int msk = 1; msk < 16; msk <<= 1) {
    s1 += __shfl_xor(s1, msk);
    s2 += __shfl_xor(s2, msk);
  }
  float mean = s1 * (1.f / 128.f);
  float rstd = rsqrtf(s2 * (1.f / 128.f) - mean * mean + 1e-5f);
  if (t < L_SEQ) {
    float* dst = &Hout[((size_t)b * L_SEQ + t) * 128];
    float4 o0 = make_float4((v[0] - mean) * rstd * nw[tm * 4 + 0] + nb[tm * 4 + 0],
                            (v[1] - mean) * rstd * nw[tm * 4 + 1] + nb[tm * 4 + 1],
                            (v[2] - mean) * rstd * nw[tm * 4 + 2] + nb[tm * 4 + 2],
                            (v[3] - mean) * rstd * nw[tm * 4 + 3] + nb[tm * 4 + 3]);
    float4 o1 = make_float4((v[4] - mean) * rstd * nw[64 + tm * 4 + 0] + nb[64 + tm * 4 + 0],
                            (v[5] - mean) * rstd * nw[64 + tm * 4 + 1] + nb[64 + tm * 4 + 1],
                            (v[6] - mean) * rstd * nw[64 + tm * 4 + 2] + nb[64 + tm * 4 + 2],
                            (v[7] - mean) * rstd * nw[64 + tm * 4 + 3] + nb[64 + tm * 4 + 3]);
    *(float4*)&dst[tm * 4] = o0;
    *(float4*)&dst[64 + tm * 4] = o1;
  }
}

// ---------------------------------------------------------------------------
// k_final  (round-3, proven)
// ---------------------------------------------------------------------------
__global__ __launch_bounds__(256) void k_final(
    const float* __restrict__ Hsrc, const float* __restrict__ fw,
    const float* __restrict__ fb, const float* __restrict__ pw,
    const float* __restrict__ pb, float* __restrict__ out) {
  int b = blockIdx.y;
  int v0 = blockIdx.x * 16;
  int tid = threadIdx.x;
  __shared__ float At[128][17];
  __shared__ float Ws[32][97];
  __shared__ float Os[96][17];
  for (int i = 0; i < 8; i++) {
    int e = tid + i * 256;
    int k = e & 127, tl = e >> 7;
    At[k][tl] = Hsrc[((size_t)b * L_SEQ + v0 + tl) * 128 + k];
  }
  __syncthreads();
  {
    int g = tid & 15, tl = tid >> 4;
    float s1 = 0.f, s2 = 0.f;
#pragma unroll
    for (int kk = 0; kk < 8; kk++) {
      float v = At[g * 8 + kk][tl];
      s1 += v;
      s2 += v * v;
    }
#pragma unroll
    for (int msk = 1; msk < 16; msk <<= 1) {
      s1 += __shfl_xor(s1, msk);
      s2 += __shfl_xor(s2, msk);
    }
    float mean = s1 * (1.f / 128.f);
    float rstd = rsqrtf(s2 * (1.f / 128.f) - mean * mean + 1e-5f);
#pragma unroll
    for (int kk = 0; kk < 8; kk++) {
      int k = g * 8 + kk;
      At[k][tl] = (At[k][tl] - mean) * rstd * fw[k] + fb[k];
    }
  }
  __syncthreads();
  int tm = tid & 15, tt = tid >> 4;
  float acc[6] = {0.f};
  for (int k0 = 0; k0 < 128; k0 += 32) {
    for (int i = 0; i < 12; i++) {
      int e = tid + i * 256;
      int ki = e & 31, p = e >> 5;
      Ws[ki][p] = pw[(size_t)p * 128 + k0 + ki];
    }
    __syncthreads();
    for (int ki = 0; ki < 32; ki++) {
      float a = At[k0 + ki][tt];
#pragma unroll
      for (int jq = 0; jq < 6; jq++)
        acc[jq] = fmaf(a, Ws[ki][tm + jq * 16], acc[jq]);
    }
    __syncthreads();
  }
#pragma unroll
  for (int jq = 0; jq < 6; jq++) {
    int p = tm + jq * 16;
    Os[p][tt] = acc[jq] + pb[p];
  }
  __syncthreads();
  for (int i = 0; i < 6; i++) {
    int e = tid + i * 256;
    int vi = e & 15, p = e >> 4;
    out[((size_t)b * 96 + p) * 1024 + v0 + vi] = Os[p][vi];
  }
}

// ---------------------------------------------------------------------------
extern "C" void kernel_launch(void* const* d_in, const int* in_sizes, int n_in,
                              void* d_out, int out_size, void* d_ws, size_t ws_size,
                              hipStream_t stream) {
  (void)in_sizes; (void)n_in; (void)out_size; (void)ws_size;
  const float* x_enc  = (const float*)d_in[0];
  const float* x_mark = (const float*)d_in[1];
  const float* emb_w  = (const float*)d_in[4];
  const float* emb_b  = (const float*)d_in[5];
  const float* ipw    = (const float*)d_in[6];
  const float* cw     = (const float*)d_in[7];
  const float* cb     = (const float*)d_in[8];
  const float* xpw    = (const float*)d_in[9];
  const float* dpw    = (const float*)d_in[10];
  const float* dpb    = (const float*)d_in[11];
  const float* A_log  = (const float*)d_in[12];
  const float* Dpar   = (const float*)d_in[13];
  const float* opw    = (const float*)d_in[14];
  const float* n1w    = (const float*)d_in[15];
  const float* n1b    = (const float*)d_in[16];
  const float* n2w    = (const float*)d_in[17];
  const float* n2b    = (const float*)d_in[18];
  const float* fw1    = (const float*)d_in[19];
  const float* fb1    = (const float*)d_in[20];
  const float* fw2    = (const float*)d_in[21];
  const float* fb2    = (const float*)d_in[22];
  const float* fnw    = (const float*)d_in[23];
  const float* fnb    = (const float*)d_in[24];
  const float* pw     = (const float*)d_in[25];
  const float* pb     = (const float*)d_in[26];

  float* ws   = (float*)d_ws;
  float* H    = ws + OFF_H;
  float* H1   = ws + OFF_H1;
  float* XZ   = ws + OFF_XZ;
  float* XCT  = ws + OFF_XCT;
  float* DLT  = ws + OFF_DLT;
  float* BmT  = ws + OFF_BMT;
  float* CmT  = ws + OFF_CMT;
  float* YT   = ws + OFF_YT;
  float* sumH = ws + OFF_H1;             // overlay: H1 unused during scan
  float* sumP = ws + OFF_H1 + SZ_SUM;

  k_embed<<<dim3(65, 8), 256, 0, stream>>>(x_enc, x_mark, emb_w, emb_b, H);
  for (int l = 0; l < 2; l++) {
    k_xz<<<dim3(33, 8, 4), 256, 0, stream>>>(H, ipw, XZ, l);
    k_mid<<<dim3(34, 8, 2), 256, 0, stream>>>(XZ, cw, cb, xpw, dpw, dpb,
                                              XCT, DLT, BmT, CmT, l);
    k_scan1<<<dim3(16, 8, 32), 64, 0, stream>>>(DLT, XCT, BmT, A_log,
                                                sumH, sumP, l);
    k_scan2<<<dim3(16, 8, 32), 64, 0, stream>>>(DLT, XCT, BmT, CmT, XZ,
                                                A_log, Dpar, sumH, sumP, YT, l);
    k_out<<<dim3(66, 8), 256, 0, stream>>>(YT, H, opw, n1w, n1b, H1, l);
    k_ffn<<<dim3(66, 8), 256, 0, stream>>>(H1, fw1, fb1, fw2, fb2, n2w, n2b, H, l);
  }
  k_final<<<dim3(64, 8), 256, 0, stream>>>(H, fnw, fnb, pw, pb, (float*)d_out);
}